// Round 5
// baseline (464.017 us; speedup 1.0000x reference)
//
#include <hip/hip_runtime.h>
#include <stdint.h>

// Problem constants
#define BB   2
#define SS   2048
#define HID  2048
#define NHQ  16
#define NKV  8
#define DD   128
// QKV fused row layout: [q: 16*128 | k: 8*128 | v: 8*128] = 4096 bf16 per (b,s)
#define QKVW 4096

typedef __bf16 v8bf   __attribute__((ext_vector_type(8)));
typedef float  f32x4  __attribute__((ext_vector_type(4)));
typedef float  f32x16 __attribute__((ext_vector_type(16)));

__device__ __forceinline__ float bf2f(ushort u) {
    union { unsigned int i; float f; } x; x.i = ((unsigned int)u) << 16; return x.f;
}
__device__ __forceinline__ ushort f2bf(float f) {
    union { float f; unsigned int i; } x; x.f = f;
    unsigned int i = x.i;
    return (ushort)((i + 0x7fffu + ((i >> 16) & 1u)) >> 16); // RNE, finite inputs
}
__device__ __forceinline__ v8bf as_bf8(uint4 u) { return __builtin_bit_cast(v8bf, u); }

__device__ __forceinline__ void store_el(float* p, float v)  { *p = v; }
__device__ __forceinline__ void store_el(ushort* p, float v) { *p = f2bf(v); }

// async global->LDS, 16B per lane; lds must be wave-uniform-base + lane*16
__device__ __forceinline__ void gll16(const ushort* g, ushort* l) {
    __builtin_amdgcn_global_load_lds(
        (const __attribute__((address_space(1))) void*)g,
        (__attribute__((address_space(3))) void*)l, 16, 0, 0);
}

// ------------------------------------------------------------- fused prep kernel
#define PREP_CAST   8192
#define PREP_WQ     (PREP_CAST)              // 64x64 tiles
#define PREP_WK     (PREP_WQ + 4096)         // 32x64
#define PREP_WV     (PREP_WK + 2048)
#define PREP_WO     (PREP_WV + 2048)         // 64x64
#define PREP_TOTAL  (PREP_WO + 4096)

__device__ __forceinline__ void tcast_body(
    const float* __restrict__ in, ushort* __restrict__ out,
    int K, int N, int bx, int by, int t)
{
    __shared__ float tile[32][33];
    int n0 = bx * 32, k0 = by * 32;
    int tx = t & 31, ty = t >> 5; // 32 x 8
#pragma unroll
    for (int i = 0; i < 32; i += 8)
        tile[ty + i][tx] = in[(size_t)(k0 + ty + i) * N + n0 + tx];
    __syncthreads();
#pragma unroll
    for (int i = 0; i < 32; i += 8)
        out[(size_t)(n0 + ty + i) * K + k0 + tx] = f2bf(tile[tx][ty + i]);
}

__global__ __launch_bounds__(256) void prep(
    const float* __restrict__ X,  const float* __restrict__ wq,
    const float* __restrict__ wk, const float* __restrict__ wv,
    const float* __restrict__ wo,
    ushort* __restrict__ Xb, ushort* __restrict__ WqkvT, ushort* __restrict__ Wot)
{
    int bid = blockIdx.x, t = threadIdx.x;
    if (bid < PREP_CAST) {
        int i = (bid * 256 + t) * 4;
        float4 v = *(const float4*)&X[i];
        ushort4 o = { f2bf(v.x), f2bf(v.y), f2bf(v.z), f2bf(v.w) };
        *(ushort4*)&Xb[i] = o;
    } else if (bid < PREP_WK) {
        int l = bid - PREP_WQ;
        tcast_body(wq, WqkvT, 2048, 2048, l & 63, l >> 6, t);
    } else if (bid < PREP_WV) {
        int l = bid - PREP_WK;
        tcast_body(wk, WqkvT + (size_t)2048 * 2048, 2048, 1024, l & 31, l >> 5, t);
    } else if (bid < PREP_WO) {
        int l = bid - PREP_WV;
        tcast_body(wv, WqkvT + (size_t)3072 * 2048, 2048, 1024, l & 31, l >> 5, t);
    } else {
        int l = bid - PREP_WO;
        tcast_body(wo, Wot, 2048, 2048, l & 63, l >> 6, t);
    }
}

// ---------------------------------------------------------------- GEMM: C = A @ Bt^T
// 128x128 block, BK=32, global_load_lds width-16, single-barrier double-buffered
// pipeline: DMA[k+1] issued right after barrier[k], drained at barrier[k+1] — the
// prefetch stays in flight across the whole compute phase.
template <typename OutT>
__global__ __launch_bounds__(256) void gemm_bt(
    const ushort* __restrict__ A, const ushort* __restrict__ Bt,
    OutT* __restrict__ C, int M, int N, int K)
{
    __shared__ __align__(16) ushort As[2][128 * 32];
    __shared__ __align__(16) ushort Bs[2][128 * 32];
    const int t = threadIdx.x;
    const int lane = t & 63, wave = t >> 6;
    const int quad = lane >> 4, l15 = lane & 15;
    const int m0 = blockIdx.y * 128, n0 = blockIdx.x * 128;
    const int wm = (wave >> 1) * 64, wn = (wave & 1) * 64;

    const f32x4 zv = {0.f, 0.f, 0.f, 0.f};
    f32x4 acc[4][4];
#pragma unroll
    for (int i = 0; i < 4; i++)
#pragma unroll
        for (int j = 0; j < 4; j++) acc[i][j] = zv;

    const int srow = t >> 2, sc8 = (t & 3) << 3;

#define DMA_AB(K0, BUF) do {                                                          \
    _Pragma("unroll")                                                                 \
    for (int ii = 0; ii < 2; ii++) {                                                  \
        gll16(&A[(size_t)(m0 + srow + ii * 64) * K + (K0) + sc8],                     \
              &As[BUF][(ii * 256 + t) * 8]);                                          \
        gll16(&Bt[(size_t)(n0 + srow + ii * 64) * K + (K0) + sc8],                    \
              &Bs[BUF][(ii * 256 + t) * 8]);                                          \
    } } while (0)

    DMA_AB(0, 0);
    const int nk = K >> 5;
    for (int ki = 0; ki < nk; ki++) {
        __syncthreads(); // drains DMA[ki] (issued one full compute phase ago)
        if (ki + 1 < nk) DMA_AB((ki + 1) << 5, (ki + 1) & 1); // in flight during compute
        const ushort* as = As[ki & 1];
        const ushort* bs = Bs[ki & 1];
        uint4 af[4], bf[4];
#pragma unroll
        for (int i = 0; i < 4; i++)
            af[i] = *(const uint4*)&as[(wm + i * 16 + l15) * 32 + quad * 8];
#pragma unroll
        for (int i = 0; i < 4; i++)
            bf[i] = *(const uint4*)&bs[(wn + i * 16 + l15) * 32 + quad * 8];
#pragma unroll
        for (int mi = 0; mi < 4; mi++)
#pragma unroll
            for (int ni = 0; ni < 4; ni++)
                acc[mi][ni] = __builtin_amdgcn_mfma_f32_16x16x32_bf16(
                    as_bf8(af[mi]), as_bf8(bf[ni]), acc[mi][ni], 0, 0, 0);
    }
#undef DMA_AB
#pragma unroll
    for (int mi = 0; mi < 4; mi++)
#pragma unroll
        for (int ni = 0; ni < 4; ni++)
#pragma unroll
            for (int r = 0; r < 4; r++) {
                int row = m0 + wm + mi * 16 + quad * 4 + r;
                int col = n0 + wn + ni * 16 + l15;
                store_el(&C[(size_t)row * N + col], acc[mi][ni][r]);
            }
}

// ------------------------------------------- per-head RMSNorm + RoPE, in place on QKV
__global__ __launch_bounds__(256) void norm_rope(
    ushort* __restrict__ qkv, const float* __restrict__ qw, const float* __restrict__ kw)
{
    int row = blockIdx.x;            // b*S + s
    int s = row & (SS - 1);
    int lane = threadIdx.x & 63, wave = threadIdx.x >> 6;
    int l = lane & 31, hsel = lane >> 5;
    float d0 = (float)(2 * l), d1 = d0 + 1.0f;
    float inv0 = expf(-d0 * (1.0f / 64.0f) * 9.210340371976184f);
    float inv1 = expf(-d1 * (1.0f / 64.0f) * 9.210340371976184f);
    float c0, s0, c1, s1;
    sincosf((float)s * inv0, &s0, &c0);
    sincosf((float)s * inv1, &s1, &c1);
    float qw0 = qw[2 * l], qw1 = qw[2 * l + 1], qy0 = qw[2 * l + 64], qy1 = qw[2 * l + 65];
    float kw0 = kw[2 * l], kw1 = kw[2 * l + 1], ky0 = kw[2 * l + 64], ky1 = kw[2 * l + 65];

#pragma unroll
    for (int pass = 0; pass < 3; pass++) {
        int h = pass * 8 + wave * 2 + hsel;
        ushort* p = qkv + (size_t)row * QKVW + h * 128;
        unsigned int ulo = *(const unsigned int*)&p[2 * l];
        unsigned int uhi = *(const unsigned int*)&p[2 * l + 64];
        float x0 = bf2f((ushort)ulo), x1 = bf2f((ushort)(ulo >> 16));
        float y0 = bf2f((ushort)uhi), y1 = bf2f((ushort)(uhi >> 16));
        float ssum = x0 * x0 + x1 * x1 + y0 * y0 + y1 * y1;
#pragma unroll
        for (int xm = 1; xm < 32; xm <<= 1) ssum += __shfl_xor(ssum, xm, 64);
        float r = rsqrtf(ssum * (1.0f / 128.0f) + 1e-6f);
        bool isq = (h < 16);
        float w0 = isq ? qw0 : kw0, w1 = isq ? qw1 : kw1;
        float v0 = isq ? qy0 : ky0, v1 = isq ? qy1 : ky1;
        float sc = isq ? 0.08838834764831845f : 1.0f; // 1/sqrt(128) folded into q
        float nx0 = w0 * (x0 * r), nx1 = w1 * (x1 * r);
        float ny0 = v0 * (y0 * r), ny1 = v1 * (y1 * r);
        float ox0 = (nx0 * c0 - ny0 * s0) * sc, ox1 = (nx1 * c1 - ny1 * s1) * sc;
        float oy0 = (ny0 * c0 + nx0 * s0) * sc, oy1 = (ny1 * c1 + nx1 * s1) * sc;
        *(unsigned int*)&p[2 * l]      = (unsigned int)f2bf(ox0) | ((unsigned int)f2bf(ox1) << 16);
        *(unsigned int*)&p[2 * l + 64] = (unsigned int)f2bf(oy0) | ((unsigned int)f2bf(oy1) << 16);
    }
}

// ---------------------------------------------------------------- flash attention
// Block = (q-tile 128, head, batch); 4 waves x 32 q-rows; 32x32x16 MFMAs.
// Single-barrier pipeline: Ks & Vt double-buffered; per iter i:
//   barrier -> DMA K[i+1] + Vt[i+1] writes (from V regs loaded 2 tiles ahead)
//   -> compute tile i.  DMA stays in flight across compute; barrier's vmcnt(0)
// drain only hits loads issued one full phase earlier. Ps is per-wave (no barrier).
// Key permutation pi: PV-key kappa = 2*l31 + nt (softmax sum is order-invariant),
// making P-stores packed b32 (conflict-free) and V pairs (vp, vp+32).
// LDS: 2*16K (Ks) + 2*16K (Vt) + 16K (Ps) = 80 KB -> 2 blocks/CU.
__global__ __launch_bounds__(256, 2) void flash_attn(
    const ushort* __restrict__ qkv, const float* __restrict__ mask, ushort* __restrict__ O)
{
    __shared__ __align__(16) ushort Ks[2][64 * 128];   // [key][dchunk ^ (key&15)]
    __shared__ __align__(16) ushort Vt[2][128 * 64];   // [d][kchunk ^ (d&7)] kappa-order
    __shared__ __align__(16) ushort Ps[4 * 32 * 64];   // per-wave [qrow][kchunk ^ (qrow&7)]
    const int t = threadIdx.x;
    const int lane = t & 63, wave = t >> 6;
    const int l31 = lane & 31, half = lane >> 5;
    const int b = blockIdx.z, h = blockIdx.y, q0 = blockIdx.x * 128;
    const int kh = h >> 1; // GQA

    // Q A-frags for 32x32x16: A[m=l31][k=half*8+j], kt=0..7 over d=128
    uint4 aq[8];
    {
        const ushort* qp = qkv + ((size_t)(b * SS + q0 + wave * 32 + l31)) * QKVW + h * 128 + half * 8;
#pragma unroll
        for (int kt = 0; kt < 8; kt++) aq[kt] = *(const uint4*)&qp[kt * 16];
    }
    f32x16 acc_o[4];
#pragma unroll
    for (int i = 0; i < 4; i++)
#pragma unroll
        for (int r = 0; r < 16; r++) acc_o[i][r] = 0.f;
    float l_part[16];
#pragma unroll
    for (int r = 0; r < 16; r++) l_part[r] = 0.f;

    const ushort* Kg = qkv + (size_t)b * SS * QKVW + 2048 + kh * 128;
    const ushort* Vg = qkv + (size_t)b * SS * QKVW + 3072 + kh * 128;

    const int vp = t & 31, vdc = t >> 5; // V staging: keys (vp, vp+32), d-group vdc
    uint4 vra[4], vrb[4];

#define LOAD_V(DST, K0) do {                                                          \
    _Pragma("unroll")                                                                 \
    for (int pass = 0; pass < 2; pass++) {                                            \
        int d0 = (vdc + pass * 8) * 8;                                                \
        DST[pass * 2 + 0] = *(const uint4*)&Vg[(size_t)((K0) + vp) * QKVW + d0];      \
        DST[pass * 2 + 1] = *(const uint4*)&Vg[(size_t)((K0) + 32 + vp) * QKVW + d0]; \
    } } while (0)

#define VT_WRITE(BUF, SRC) do {                                                       \
    _Pragma("unroll")                                                                 \
    for (int pass = 0; pass < 2; pass++) {                                            \
        const ushort* pa = (const ushort*)&SRC[pass * 2 + 0];                         \
        const ushort* pb = (const ushort*)&SRC[pass * 2 + 1];                         \
        int d0 = (vdc + pass * 8) * 8;                                                \
        _Pragma("unroll")                                                             \
        for (int j = 0; j < 8; j++) {                                                 \
            int d = d0 + j;                                                           \
            int cp = (vp >> 2) ^ (d & 7);                                             \
            unsigned int val = (unsigned int)pa[j] | ((unsigned int)pb[j] << 16);     \
            *(unsigned int*)&Vt[BUF][d * 64 + cp * 8 + 2 * (vp & 3)] = val;           \
        } } } while (0)

#define DMA_K(K0, BUF) do {                                                           \
    _Pragma("unroll")                                                                 \
    for (int ii = 0; ii < 4; ii++) {                                                  \
        int chunk = ii * 256 + t;                                                     \
        int row = chunk >> 4, cpz = chunk & 15;                                       \
        int cl = cpz ^ (row & 15);                                                    \
        gll16(&Kg[(size_t)((K0) + row) * QKVW + cl * 8], &Ks[BUF][chunk * 8]);        \
    } } while (0)

    const int pwb = wave * 2048; // Ps wave base (32*64)

    // prologue: V tiles 0,1 into regs; K tile 0 via DMA; Vt[0] built
    LOAD_V(vra, 0);
    LOAD_V(vrb, 64);
    DMA_K(0, 0);
    __syncthreads(); // drain prologue loads/DMA
    VT_WRITE(0, vra);

    for (int i = 0; i < 32; i++) {
        const int k0 = i * 64;
        __syncthreads(); // Vt[i] visible; DMA K[i] drained (issued one phase ago)
        if (i + 1 < 32) {
            DMA_K((i + 1) * 64, (i + 1) & 1);       // in flight during compute[i]
            if ((i + 1) & 1) { VT_WRITE(1, vrb); } else { VT_WRITE(0, vra); }
            if (i + 2 < 32) {
                if ((i + 2) & 1) { LOAD_V(vrb, (i + 2) * 64); }
                else             { LOAD_V(vra, (i + 2) * 64); }
            }
        }
        const ushort* ksb = Ks[i & 1];
        const ushort* vtb = Vt[i & 1];

        // scores: S = Q K^T, 2 col-tiles of 32 keys, 8 d-steps of 16
        f32x16 sc[2];
#pragma unroll
        for (int nt = 0; nt < 2; nt++) {
#pragma unroll
            for (int r = 0; r < 16; r++) sc[nt][r] = 0.f;
#pragma unroll
            for (int kt = 0; kt < 8; kt++) {
                int cp = (kt * 2 + half) ^ (l31 & 15);
                uint4 bk = *(const uint4*)&ksb[(nt * 32 + l31) * 128 + cp * 8];
                sc[nt] = __builtin_amdgcn_mfma_f32_32x32x16_bf16(
                    as_bf8(aq[kt]), as_bf8(bk), sc[nt], 0, 0, 0);
            }
        }
        // mask + exp + partial row sums
#pragma unroll
        for (int nt = 0; nt < 2; nt++) {
            float mv = mask[b * SS + k0 + nt * 32 + l31];
            float madd = (1.0f - mv) * -1e30f;
#pragma unroll
            for (int r = 0; r < 16; r++) {
                float pv = __expf(sc[nt][r] + madd);
                sc[nt][r] = pv;
                l_part[r] += pv;
            }
        }
        // P -> per-wave LDS, kappa-order: lane's (nt=0,nt=1) pair packs into one b32
#pragma unroll
        for (int r = 0; r < 16; r++) {
            int prow = (r & 3) + 8 * (r >> 2) + 4 * half;
            int cp = (l31 >> 2) ^ (prow & 7);
            unsigned int pv2 = (unsigned int)f2bf(sc[0][r]) | ((unsigned int)f2bf(sc[1][r]) << 16);
            *(unsigned int*)&Ps[pwb + prow * 64 + cp * 8 + 2 * (l31 & 3)] = pv2;
        }
        // PV: A = P[32 q x 64 kappa], B = Vt[kappa x d], 4 k-steps, 4 d-tiles
#pragma unroll
        for (int kt2 = 0; kt2 < 4; kt2++) {
            int kc = kt2 * 2 + half;
            uint4 ap = *(const uint4*)&Ps[pwb + l31 * 64 + (kc ^ (l31 & 7)) * 8];
#pragma unroll
            for (int nt = 0; nt < 4; nt++) {
                int d = nt * 32 + l31;
                uint4 bv = *(const uint4*)&vtb[d * 64 + (kc ^ (l31 & 7)) * 8];
                acc_o[nt] = __builtin_amdgcn_mfma_f32_32x32x16_bf16(
                    as_bf8(ap), as_bf8(bv), acc_o[nt], 0, 0, 0);
            }
        }
    }
#undef LOAD_V
#undef VT_WRITE
#undef DMA_K
    // final row-sum reduction over the 32 lanes sharing each row set
    float l_i[16];
#pragma unroll
    for (int r = 0; r < 16; r++) {
        float s = l_part[r];
#pragma unroll
        for (int xm = 1; xm < 32; xm <<= 1) s += __shfl_xor(s, xm, 64);
        l_i[r] = 1.0f / s;
    }
    // epilogue
#pragma unroll
    for (int nt = 0; nt < 4; nt++)
#pragma unroll
        for (int r = 0; r < 16; r++) {
            int prow = (r & 3) + 8 * (r >> 2) + 4 * half;
            int qrow = q0 + wave * 32 + prow;
            int d = nt * 32 + l31;
            float v = acc_o[nt][r] * l_i[r];
            O[((size_t)(b * SS + qrow)) * (NHQ * DD) + h * 128 + d] = f2bf(v);
        }
}

// ---------------------------------------------------------------- launch
extern "C" void kernel_launch(void* const* d_in, const int* in_sizes, int n_in,
                              void* d_out, int out_size, void* d_ws, size_t ws_size,
                              hipStream_t stream)
{
    const float* X    = (const float*)d_in[0];
    const float* mask = (const float*)d_in[1];
    const float* wq   = (const float*)d_in[2];
    const float* wk   = (const float*)d_in[3];
    const float* wv   = (const float*)d_in[4];
    const float* wo   = (const float*)d_in[5];
    const float* qnw  = (const float*)d_in[6];
    const float* knw  = (const float*)d_in[7];
    float* out = (float*)d_out;

    const size_t M = (size_t)BB * SS; // 4096
    ushort* Xb    = (ushort*)d_ws;                       // 4096x2048
    ushort* WqkvT = Xb    + M * HID;                     // 4096x2048 (Wq^T|Wk^T|Wv^T rows)
    ushort* Wot   = WqkvT + (size_t)4096 * HID;          // 2048x2048
    ushort* QKV   = Wot   + (size_t)2048 * 2048;         // 4096x4096
    ushort* Obuf  = QKV   + M * QKVW;                    // 4096x2048

    prep<<<PREP_TOTAL, 256, 0, stream>>>(X, wq, wk, wv, wo, Xb, WqkvT, Wot);

    // fused QKV projection: (4096,2048) @ (4096,2048)^T -> (4096,4096)
    gemm_bt<ushort><<<dim3(4096 / 128, 4096 / 128), 256, 0, stream>>>(Xb, WqkvT, QKV, 4096, 4096, 2048);

    norm_rope<<<(int)M, 256, 0, stream>>>(QKV, qnw, knw);

    flash_attn<<<dim3(SS / 128, NHQ, BB), 256, 0, stream>>>(QKV, mask, Obuf);

    // out projection: (4096,2048) @ (2048,2048)^T -> fp32 d_out
    gemm_bt<float><<<dim3(2048 / 128, 4096 / 128), 256, 0, stream>>>(Obuf, Wot, out, 4096, 2048, 2048);
}